// Round 8
// baseline (368.577 us; speedup 1.0000x reference)
//
#include <hip/hip_runtime.h>
#include <hip/hip_bf16.h>

// Problem constants
constexpr int kB  = 1024;
constexpr int kV  = 6890;
constexpr int kJ  = 24;
constexpr int kNB = 10;
constexpr int kP  = 207;   // 23*9
constexpr int kH  = 17;

constexpr int kN   = kV * 3;      // 20670
constexpr int kKP  = 224;         // K1 padded: 207 pf + 10 betas + 1 vt + 6 zero
constexpr int kNT  = 1296;        // n-tiles of 16 (N1_pad = 20736)
constexpr int kNP  = kNT * 16;    // 20736
constexpr int kVC  = 862;         // v-chunk for k_js (8 chunks)
constexpr int kVT  = 432;         // v-tiles of 16 (V_pad = 6912)

// Output layout (flat concat, FP32 elements)
constexpr size_t O_VERTS  = 0;
constexpr size_t O_JOINTS = (size_t)kB * kV * 3;              // 21166080
constexpr size_t O_ROT    = O_JOINTS + (size_t)kB * kJ * 3;   // 21239808
constexpr size_t O_JFV    = O_ROT + (size_t)kB * kJ * 9;      // 21460992

// Workspace layout (fp32 elements) — peak 12.0 MB, same as round 7
constexpr size_t WS_JS   = 0;                        // 792
constexpr size_t WS_A    = 1024;                     // kB*288
constexpr size_t WS_PF   = WS_A + (size_t)kB * 288;  // kB*207   (dead after k_prep_a)
constexpr size_t WS_ROOT = WS_PF + (size_t)kB * kP;  // kB*3
constexpr size_t WS_JFV  = WS_ROOT + (size_t)kB * 3; // kB*51
constexpr size_t WS_A1   = 563200;                   // 1024*224 ushort
constexpr size_t WS_B1   = WS_A1 + 114688;           // 1296*7*512 ushort (dead after k_fused)
// overlays:
constexpr size_t WS_W    = WS_PF;                    // 432*512 ushort = 110592 fl <= 211968
constexpr size_t WS_JHT  = WS_B1;                    // kV*17 floats, after k_fused

typedef __attribute__((ext_vector_type(8))) short short8;
typedef __attribute__((ext_vector_type(4))) float float4v;

__device__ __forceinline__ unsigned short f2bf(float f) {
    unsigned u = __float_as_uint(f);
    unsigned r = (u + 0x7FFFu + ((u >> 16) & 1u)) >> 16;  // RNE
    return (unsigned short)r;
}

// inline classifier: returns true if p (one of the two 165360-el inputs) is
// lbs_weights (its first 24 entries = row0 sum to exactly 1).
__device__ __forceinline__ bool is_lbs(const float* __restrict__ p) {
    float s = 0.f;
    #pragma unroll
    for (int i = 0; i < kJ; i++) s += p[i];
    return fabsf(s - 1.0f) < 0.5f;
}

// ---------------------------------------------------------------------------
// k_js: partial[(j*8+c)*33 + i] = sum over v-chunk c of Jreg[j,v]*[sd|vt].
// ---------------------------------------------------------------------------
__global__ __launch_bounds__(256) void k_js(
    const float* __restrict__ amb0,
    const float* __restrict__ amb1,
    const float* __restrict__ sd,
    const float* __restrict__ vt,
    float* __restrict__ partial)
{
    const float* Jreg = is_lbs(amb0) ? amb1 : amb0;
    int j = blockIdx.x;
    int c = blockIdx.y;
    int t = threadIdx.x;
    int lane = t & 63;
    int wave = t >> 6;

    float acc[33];
    #pragma unroll
    for (int i = 0; i < 33; i++) acc[i] = 0.f;

    int vend = min(kVC * (c + 1), kV);
    for (int v = kVC * c + t; v < vend; v += 256) {
        float w = Jreg[j * kV + v];
        const float* sdp = sd + (size_t)v * 30;
        #pragma unroll
        for (int k = 0; k < 3; k++) {
            #pragma unroll
            for (int l = 0; l < kNB; l++)
                acc[k * 11 + l] += w * sdp[k * 10 + l];
            acc[k * 11 + 10] += w * vt[v * 3 + k];
        }
    }
    #pragma unroll
    for (int off = 32; off > 0; off >>= 1) {
        #pragma unroll
        for (int i = 0; i < 33; i++)
            acc[i] += __shfl_down(acc[i], off, 64);
    }
    __shared__ float red[4][33];
    if (lane == 0) {
        #pragma unroll
        for (int i = 0; i < 33; i++) red[wave][i] = acc[i];
    }
    __syncthreads();
    if (t < 33) {
        float s = red[0][t] + red[1][t] + red[2][t] + red[3][t];
        partial[((size_t)j * 8 + c) * 33 + t] = s;
    }
}

__global__ __launch_bounds__(1024) void k_js_reduce(
    const float* __restrict__ partial,
    float* __restrict__ js)
{
    int t = threadIdx.x;
    if (t < 24 * 33) {
        int j = t / 33, i = t % 33;
        float s = 0.f;
        #pragma unroll
        for (int c = 0; c < 8; c++) s += partial[((size_t)j * 8 + c) * 33 + i];
        js[t] = s;
    }
}

// ---------------------------------------------------------------------------
// k_pose: per-batch rodrigues + FK chain + A matrices.
// ---------------------------------------------------------------------------
__global__ __launch_bounds__(64) void k_pose(
    const float* __restrict__ pose,
    const float* __restrict__ betas,
    const float* __restrict__ gor,
    const float* __restrict__ js,
    float* __restrict__ wsA,
    float* __restrict__ wsPF,
    float* __restrict__ wsRoot,
    float* __restrict__ out)
{
    __shared__ float Rsh[kJ][9];
    __shared__ float Jr[kJ][3];
    __shared__ float G[kJ][12];

    int b = blockIdx.x;
    int t = threadIdx.x;

    if (t < kJ) {
        float rx, ry, rz;
        if (t == 0) {
            rx = gor[b * 3 + 0]; ry = gor[b * 3 + 1]; rz = gor[b * 3 + 2];
        } else {
            int o = b * 69 + (t - 1) * 3;
            rx = pose[o]; ry = pose[o + 1]; rz = pose[o + 2];
        }
        float ex = rx + 1e-8f, ey = ry + 1e-8f, ez = rz + 1e-8f;
        float ang = sqrtf(ex * ex + ey * ey + ez * ez);
        float x = rx / ang, y = ry / ang, z = rz / ang;
        float s = sinf(ang), c = cosf(ang), oc = 1.0f - c;
        float r[9];
        r[0] = 1.0f - oc * (y * y + z * z);
        r[1] = -s * z + oc * (x * y);
        r[2] =  s * y + oc * (x * z);
        r[3] =  s * z + oc * (x * y);
        r[4] = 1.0f - oc * (x * x + z * z);
        r[5] = -s * x + oc * (y * z);
        r[6] = -s * y + oc * (x * z);
        r[7] =  s * x + oc * (y * z);
        r[8] = 1.0f - oc * (x * x + y * y);
        #pragma unroll
        for (int i = 0; i < 9; i++) Rsh[t][i] = r[i];
        float* ro = out + O_ROT + (size_t)b * (kJ * 9) + (size_t)t * 9;
        #pragma unroll
        for (int i = 0; i < 9; i++) ro[i] = r[i];
        if (t >= 1) {
            float* pf = wsPF + (size_t)b * kP + (size_t)(t - 1) * 9;
            #pragma unroll
            for (int i = 0; i < 9; i++)
                pf[i] = r[i] - ((i == 0 || i == 4 || i == 8) ? 1.0f : 0.0f);
        }
        float bt[kNB];
        #pragma unroll
        for (int l = 0; l < kNB; l++) bt[l] = betas[b * kNB + l];
        #pragma unroll
        for (int k = 0; k < 3; k++) {
            const float* row = js + (t * 3 + k) * 11;
            float acc = row[10];
            #pragma unroll
            for (int l = 0; l < kNB; l++) acc += bt[l] * row[l];
            Jr[t][k] = acc;
        }
    }
    __syncthreads();

    if (t == 0) {
        const int par[kJ] = {-1,0,0,0,1,2,3,4,5,6,7,8,9,9,9,12,13,14,16,17,18,19,20,21};
        #pragma unroll
        for (int m = 0; m < 3; m++) {
            #pragma unroll
            for (int n = 0; n < 3; n++) G[0][m * 4 + n] = Rsh[0][m * 3 + n];
            G[0][m * 4 + 3] = Jr[0][m];
        }
        for (int i = 1; i < kJ; i++) {
            int p = par[i];
            float rel[3];
            #pragma unroll
            for (int k = 0; k < 3; k++) rel[k] = Jr[i][k] - Jr[p][k];
            #pragma unroll
            for (int m = 0; m < 3; m++) {
                float g0 = G[p][m * 4 + 0], g1 = G[p][m * 4 + 1], g2 = G[p][m * 4 + 2];
                #pragma unroll
                for (int n = 0; n < 3; n++) {
                    G[i][m * 4 + n] = g0 * Rsh[i][0 * 3 + n]
                                    + g1 * Rsh[i][1 * 3 + n]
                                    + g2 * Rsh[i][2 * 3 + n];
                }
                G[i][m * 4 + 3] = g0 * rel[0] + g1 * rel[1] + g2 * rel[2]
                                + G[p][m * 4 + 3];
            }
        }
    }
    __syncthreads();

    if (t < kJ) {
        float* Aj = wsA + (size_t)b * 288 + (size_t)t * 12;
        float* jo = out + O_JOINTS + (size_t)b * (kJ * 3) + (size_t)t * 3;
        #pragma unroll
        for (int m = 0; m < 3; m++) {
            float g0 = G[t][m * 4 + 0], g1 = G[t][m * 4 + 1], g2 = G[t][m * 4 + 2];
            Aj[m * 4 + 0] = g0;
            Aj[m * 4 + 1] = g1;
            Aj[m * 4 + 2] = g2;
            Aj[m * 4 + 3] = G[t][m * 4 + 3]
                          - (g0 * Jr[t][0] + g1 * Jr[t][1] + g2 * Jr[t][2]);
            jo[m] = G[t][m * 4 + 3] - G[0][m * 4 + 3];
        }
        if (t == 0) {
            #pragma unroll
            for (int k = 0; k < 3; k++) wsRoot[b * 3 + k] = G[0][k * 4 + 3];
        }
    }
}

// ---------------------------------------------------------------------------
// k_prep_b: swizzled bf16 B1 (K=224 x N=20736): posedirs | shapedirs^T | vt.
// ---------------------------------------------------------------------------
__global__ __launch_bounds__(256) void k_prep_b(
    const float* __restrict__ pd,
    const float* __restrict__ sd,
    const float* __restrict__ vt,
    unsigned short* __restrict__ bswz)
{
    __shared__ unsigned short lds[kKP][68];
    int g = blockIdx.x;
    int n0 = g * 64;
    int t = threadIdx.x;

    for (int kbase = 0; kbase < kKP; kbase += 4) {
        int k = kbase + (t >> 6);
        int nl = t & 63;
        int n = n0 + nl;
        float val = 0.f;
        if (n < kN) {
            if (k < kP)                 val = pd[(size_t)k * kN + n];
            else if (k < kP + kNB)      val = sd[(size_t)n * kNB + (k - kP)];
            else if (k == kP + kNB)     val = vt[n];
        }
        lds[k][nl] = f2bf(val);
    }
    __syncthreads();

    #pragma unroll 1
    for (int tt = 0; tt < 4; tt++) {
        int ntile = g * 4 + tt;
        #pragma unroll 1
        for (int kt = 0; kt < 7; kt++) {
            size_t base = ((size_t)ntile * 7 + kt) * 512;
            #pragma unroll
            for (int u = 0; u < 2; u++) {
                int e = t * 2 + u;
                int quad = e >> 7, rem = e & 127;
                int nin = rem >> 3, kin = rem & 7;
                int k = kt * 32 + quad * 8 + kin;
                bswz[base + e] = lds[k][tt * 16 + nin];
            }
        }
    }
}

// ---------------------------------------------------------------------------
// k_prep_a: swizzled bf16 A1 (M=1024 x K=224): pf | betas | 1.0 | 0.
// ---------------------------------------------------------------------------
__global__ __launch_bounds__(256) void k_prep_a(
    const float* __restrict__ wsPF,
    const float* __restrict__ betas,
    unsigned short* __restrict__ aswz)
{
    int mtile = blockIdx.x;   // 0..63
    int t = threadIdx.x;
    for (int e = t; e < 16 * kKP; e += 256) {
        int kt = e >> 9, r = e & 511;
        int quad = r >> 7, min_ = (r >> 3) & 15, kin = r & 7;
        int k = kt * 32 + quad * 8 + kin;
        int b = mtile * 16 + min_;
        float val = 0.f;
        if (k < kP)             val = wsPF[(size_t)b * kP + k];
        else if (k < kP + kNB)  val = betas[(size_t)b * kNB + (k - kP)];
        else if (k == kP + kNB) val = 1.0f;
        aswz[((size_t)mtile * 7 + kt) * 512 + r] = f2bf(val);
    }
}

// ---------------------------------------------------------------------------
// k_prep_w: swizzled bf16 W (A-operand of blend GEMM): tile v x j(K=32).
// ---------------------------------------------------------------------------
__global__ __launch_bounds__(256) void k_prep_w(
    const float* __restrict__ amb0,
    const float* __restrict__ amb1,
    unsigned short* __restrict__ wswz)
{
    const float* W = is_lbs(amb0) ? amb0 : amb1;
    int vtile = blockIdx.x;   // 0..431
    int t = threadIdx.x;
    #pragma unroll
    for (int u = 0; u < 2; u++) {
        int e = t * 2 + u;
        int quad = e >> 7, min_ = (e >> 3) & 15, kin = e & 7;
        int v = vtile * 16 + min_;
        int j = quad * 8 + kin;
        float val = (v < kV && j < kJ) ? W[(size_t)v * kJ + j] : 0.f;
        wswz[(size_t)vtile * 512 + e] = f2bf(val);
    }
}

// ---------------------------------------------------------------------------
// k_fused: per block (b-tile 16 batches x v-tile 64 vertices):
//   GEMM1: C1[16b x 192n] = A1 @ B1  (MFMA, 7 k-steps)  -> LDS (fp32 vph)
//   GEMM2: C2[64v x (16b x 16c)] = W @ A'  (MFMA, 1 k-step, A' built in LDS)
//   epilogue: o[m] = sum_k Tv[m,k]*vph[k] - root; quad shfl_xor reduce; write.
// ---------------------------------------------------------------------------
__global__ __launch_bounds__(256) void k_fused(
    const unsigned short* __restrict__ A1,
    const unsigned short* __restrict__ B1,
    const unsigned short* __restrict__ Wswz,
    const float* __restrict__ wsA,
    const float* __restrict__ wsRoot,
    float* __restrict__ out)
{
    __shared__ float c1[16 * 193];            // vph: [b_local][vloc*3+k], stride 193
    __shared__ unsigned short a2[16 * 512];   // blend B-frags, one per batch

    int t = threadIdx.x;
    int lane = t & 63;
    int w = t >> 6;
    int btile = blockIdx.x;       // 0..63  -> batches b0..b0+15
    int b0 = btile * 16;
    int vt0 = blockIdx.y * 4;     // v-tiles (of 16); v0 = blockIdx.y*64

    // build A' frags in LDS: a2[btl*512 + quad*128 + nin*8 + kin] = A[b,j,c]
    for (int e = t; e < 16 * 512; e += 256) {
        int btl = e >> 9, r = e & 511;
        int quad = r >> 7, nin = (r >> 3) & 15, kin = r & 7;
        int j = quad * 8 + kin;
        float val = (j < kJ && nin < 12)
                  ? wsA[(size_t)(b0 + btl) * 288 + j * 12 + nin] : 0.f;
        a2[e] = f2bf(val);
    }

    // GEMM1: wave w handles local n-tiles w*3 .. w*3+2
    float4v acc1[3];
    #pragma unroll
    for (int jj = 0; jj < 3; jj++) acc1[jj] = (float4v){0.f, 0.f, 0.f, 0.f};
    #pragma unroll
    for (int kt = 0; kt < 7; kt++) {
        short8 af = *(const short8*)(A1 + ((size_t)btile * 7 + kt) * 512 + lane * 8);
        #pragma unroll
        for (int jj = 0; jj < 3; jj++) {
            int nt = blockIdx.y * 12 + w * 3 + jj;
            short8 bf = *(const short8*)(B1 + ((size_t)nt * 7 + kt) * 512 + lane * 8);
            acc1[jj] = __builtin_amdgcn_mfma_f32_16x16x32_bf16(af, bf, acc1[jj], 0, 0, 0);
        }
    }
    int col = lane & 15, quad = lane >> 4;
    #pragma unroll
    for (int jj = 0; jj < 3; jj++) {
        #pragma unroll
        for (int reg = 0; reg < 4; reg++) {
            int brow = quad * 4 + reg;
            c1[brow * 193 + (w * 3 + jj) * 16 + col] = acc1[jj][reg];
        }
    }
    __syncthreads();

    // GEMM2: wave w covers batches b0 + w*4 + jw (jw=0..3), v-tiles i=0..3
    short8 wa[4];
    #pragma unroll
    for (int i = 0; i < 4; i++)
        wa[i] = *(const short8*)(Wswz + (size_t)(vt0 + i) * 512 + lane * 8);
    float4v acc2[4][4];
    #pragma unroll
    for (int i = 0; i < 4; i++)
        #pragma unroll
        for (int jw = 0; jw < 4; jw++)
            acc2[i][jw] = (float4v){0.f, 0.f, 0.f, 0.f};
    #pragma unroll
    for (int jw = 0; jw < 4; jw++) {
        short8 bfr = *(const short8*)(a2 + (w * 4 + jw) * 512 + lane * 8);
        #pragma unroll
        for (int i = 0; i < 4; i++)
            acc2[i][jw] = __builtin_amdgcn_mfma_f32_16x16x32_bf16(wa[i], bfr, acc2[i][jw], 0, 0, 0);
    }

    // epilogue
    int kk = col & 3, m = col >> 2;
    #pragma unroll
    for (int jw = 0; jw < 4; jw++) {
        int bl = w * 4 + jw;
        int b = b0 + bl;
        float rt = (m < 3) ? wsRoot[(size_t)b * 3 + m] : 0.f;
        #pragma unroll
        for (int i = 0; i < 4; i++) {
            #pragma unroll
            for (int reg = 0; reg < 4; reg++) {
                int vloc = i * 16 + quad * 4 + reg;
                float h = (kk < 3) ? c1[bl * 193 + vloc * 3 + kk] : 1.0f;
                float o = acc2[i][jw][reg] * h;
                o += __shfl_xor(o, 1, 64);
                o += __shfl_xor(o, 2, 64);
                int vg = blockIdx.y * 64 + vloc;
                if (kk == 0 && m < 3 && vg < kV)
                    out[O_VERTS + ((size_t)b * kV + vg) * 3 + m] = o - rt;
            }
        }
    }
}

// ---------------------------------------------------------------------------
// k_prep_jh: JhT[v*17 + j] = Jh[j*kV + v]   (runs after k_fused; overlays B1)
// ---------------------------------------------------------------------------
__global__ __launch_bounds__(256) void k_prep_jh(
    const float* __restrict__ Jh,
    float* __restrict__ jht)
{
    int v = blockIdx.x * 256 + threadIdx.x;
    if (v >= kV) return;
    #pragma unroll
    for (int j = 0; j < kH; j++)
        jht[(size_t)v * kH + j] = Jh[(size_t)j * kV + v];
}

// ---------------------------------------------------------------------------
// k_jfv: jfv[b,j,k] = sum_v JhT[v,j] * verts_out[b,v,k]
// ---------------------------------------------------------------------------
__global__ __launch_bounds__(256) void k_jfv(
    const float* __restrict__ jht,
    const float* __restrict__ vertsOut,
    float* __restrict__ wsJfv)
{
    int b = blockIdx.x;
    int t = threadIdx.x;
    int lane = t & 63;
    int wave = t >> 6;

    float acc[kH * 3];
    #pragma unroll
    for (int i = 0; i < kH * 3; i++) acc[i] = 0.f;

    for (int v = t; v < kV; v += 256) {
        const float* vpt = vertsOut + ((size_t)b * kV + v) * 3;
        float vx = vpt[0], vy = vpt[1], vz = vpt[2];
        const float* jt = jht + (size_t)v * kH;
        #pragma unroll
        for (int j = 0; j < kH; j++) {
            float wj = jt[j];
            acc[j * 3 + 0] += wj * vx;
            acc[j * 3 + 1] += wj * vy;
            acc[j * 3 + 2] += wj * vz;
        }
    }
    #pragma unroll
    for (int off = 32; off > 0; off >>= 1) {
        #pragma unroll
        for (int i = 0; i < kH * 3; i++)
            acc[i] += __shfl_down(acc[i], off, 64);
    }
    __shared__ float partial[4][kH * 3];
    if (lane == 0) {
        #pragma unroll
        for (int i = 0; i < kH * 3; i++) partial[wave][i] = acc[i];
    }
    __syncthreads();
    if (t < kH * 3) {
        float s = partial[0][t] + partial[1][t] + partial[2][t] + partial[3][t];
        wsJfv[(size_t)b * 51 + t] = s;
    }
}

__global__ __launch_bounds__(64) void k_jfv_out(
    const float* __restrict__ wsJfv,
    float* __restrict__ out)
{
    int b = blockIdx.x;
    int t = threadIdx.x;
    if (t < kH * 3) {
        int k = t % 3;
        float val = wsJfv[(size_t)b * 51 + t] - wsJfv[(size_t)b * 51 + k];
        out[O_JFV + (size_t)b * 51 + t] = val;
    }
}

extern "C" void kernel_launch(void* const* d_in, const int* in_sizes, int n_in,
                              void* d_out, int out_size, void* d_ws, size_t ws_size,
                              hipStream_t stream) {
    const float *pose = nullptr, *betas = nullptr, *gor = nullptr, *vt = nullptr,
                *sd = nullptr, *pd = nullptr, *Jh = nullptr;
    const float *amb0 = nullptr, *amb1 = nullptr;
    for (int i = 0; i < n_in; i++) {
        const float* p = (const float*)d_in[i];
        switch (in_sizes[i]) {
            case 70656:   pose  = p; break;
            case 10240:   betas = p; break;
            case 3072:    gor   = p; break;
            case 20670:   vt    = p; break;
            case 206700:  sd    = p; break;
            case 4278690: pd    = p; break;
            case 117130:  Jh    = p; break;
            case 165360:  if (!amb0) amb0 = p; else amb1 = p; break;
            default: break;
        }
    }

    float* ws = (float*)d_ws;
    float* js      = ws + WS_JS;
    float* wsA     = ws + WS_A;
    float* wsPF    = ws + WS_PF;
    float* wsRoot  = ws + WS_ROOT;
    float* wsJfv   = ws + WS_JFV;
    unsigned short* a1swz = (unsigned short*)(ws + WS_A1);
    unsigned short* b1swz = (unsigned short*)(ws + WS_B1);
    unsigned short* wswz  = (unsigned short*)(ws + WS_W);   // overlays wsPF (dead)
    float* jspart  = ws + WS_A1;    // overlay: dead before k_prep_a
    float* jht     = ws + WS_JHT;   // overlay: dead after k_fused

    float* out = (float*)d_out;

    k_js<<<dim3(kJ, 8), dim3(256), 0, stream>>>(amb0, amb1, sd, vt, jspart);
    k_js_reduce<<<dim3(1), dim3(1024), 0, stream>>>(jspart, js);
    k_pose<<<dim3(kB), dim3(64), 0, stream>>>(pose, betas, gor, js, wsA, wsPF, wsRoot, out);
    k_prep_b<<<dim3(kNP / 64), dim3(256), 0, stream>>>(pd, sd, vt, b1swz);
    k_prep_a<<<dim3(64), dim3(256), 0, stream>>>(wsPF, betas, a1swz);
    k_prep_w<<<dim3(kVT), dim3(256), 0, stream>>>(amb0, amb1, wswz);   // after prep_a!
    k_fused<<<dim3(64, kVT / 4), dim3(256), 0, stream>>>(
        a1swz, b1swz, wswz, wsA, wsRoot, out);
    k_prep_jh<<<dim3((kV + 255) / 256), dim3(256), 0, stream>>>(Jh, jht);
    k_jfv<<<dim3(kB), dim3(256), 0, stream>>>(jht, out + O_VERTS, wsJfv);
    k_jfv_out<<<dim3(kB), dim3(64), 0, stream>>>(wsJfv, out);
}